// Round 1
// baseline (3294.873 us; speedup 1.0000x reference)
//
#include <hip/hip_runtime.h>

#define BB 32
#define NN 128
#define EE 16384
#define DD 72
#define HH 72
#define AA 4
#define ROWS_E (BB*EE)     // 524288
#define ROWS_N (BB*NN)     // 4096
#define EPS_BN 1e-5f

// d_out layout (floats): h_out, x_out, m
#define HOUT_OFF 0
#define XOUT_OFF (ROWS_N*DD)            // 294912
#define M_OFF    (XOUT_OFF + ROWS_N*4)  // 311296

// ws layout (floats)
#define ST1_OFF 0                        // sum[72], sumsq[72], mean[72]@144, inv[72]@216
#define ST2_OFF 512
#define AGG_OFF 1024
#define CNT_OFF (AGG_OFF + ROWS_N*4)     // 17408
#define MAGG_OFF (CNT_OFF + ROWS_N)      // 21504
#define Z2_OFF (MAGG_OFF + ROWS_N*HH)    // 316416
#define ZERO_FLOATS Z2_OFF               // atomics region needing zero-init

__device__ __forceinline__ float psi_f(float p) {
    return copysignf(log1pf(fabsf(p)), p);
}

// ---------------- K1: z1 = feat @ We1, feat = [hi, hj, psi(|xd|_M), psi(<xi,xj>_M)]
__global__ __launch_bounds__(256) void k_edge_gemm1(
    const float* __restrict__ h, const float* __restrict__ x,
    const int* __restrict__ ei, const int* __restrict__ ej,
    const float* __restrict__ We1, float* __restrict__ z1)
{
    int row = blockIdx.x * 256 + threadIdx.x;     // < ROWS_E
    int b = row >> 14;                             // E = 16384
    int i = ei[row], j = ej[row];
    const float* hb = h + (size_t)b * NN * DD;
    const float4* hi4 = (const float4*)(hb + i * DD);
    const float4* hj4 = (const float4*)(hb + j * DD);
    float4 xi = *(const float4*)(x + ((size_t)b * NN + i) * 4);
    float4 xj = *(const float4*)(x + ((size_t)b * NN + j) * 4);
    float d0 = xi.x - xj.x, d1 = xi.y - xj.y, d2 = xi.z - xj.z, d3 = xi.w - xj.w;
    float nrm = d0*d0 - d1*d1 - d2*d2 - d3*d3;                 // Minkowski norm^2
    float dot = xi.x*xj.x - xi.y*xj.y - xi.z*xj.z - xi.w*xj.w; // Minkowski dot
    float norms = psi_f(nrm);
    float dots  = psi_f(dot);

    float acc[HH];
    #pragma unroll
    for (int c = 0; c < HH; c++)
        acc[c] = norms * We1[144*HH + c] + dots * We1[145*HH + c];

    for (int kk = 0; kk < 18; kk++) {
        float4 a  = hi4[kk];
        float4 bj = hj4[kk];
        const float* w0 = We1 + (kk*4) * HH;          // hi rows
        const float* w1 = We1 + (72 + kk*4) * HH;     // hj rows
        #pragma unroll
        for (int c = 0; c < HH; c++) {
            acc[c] += a.x*w0[c] + a.y*w0[HH+c] + a.z*w0[2*HH+c] + a.w*w0[3*HH+c]
                    + bj.x*w1[c] + bj.y*w1[HH+c] + bj.z*w1[2*HH+c] + bj.w*w1[3*HH+c];
        }
    }
    float4* o4 = (float4*)(z1 + (size_t)row * HH);
    #pragma unroll
    for (int kk = 0; kk < 18; kk++)
        o4[kk] = make_float4(acc[4*kk], acc[4*kk+1], acc[4*kk+2], acc[4*kk+3]);
}

// ---------------- per-channel sum/sumsq over rows (for BatchNorm)
__global__ void k_stats(const float* __restrict__ z, int rows, float* __restrict__ st)
{
    __shared__ float ssum[4][HH];
    __shared__ float ssq[4][HH];
    int c = threadIdx.x;      // 0..71
    int ty = threadIdx.y;     // 0..3
    float s = 0.f, q = 0.f;
    for (int r = blockIdx.x * 4 + ty; r < rows; r += gridDim.x * 4) {
        float v = z[(size_t)r * HH + c];
        s += v; q += v * v;
    }
    ssum[ty][c] = s; ssq[ty][c] = q;
    __syncthreads();
    if (ty == 0) {
        s = ssum[0][c] + ssum[1][c] + ssum[2][c] + ssum[3][c];
        q = ssq[0][c] + ssq[1][c] + ssq[2][c] + ssq[3][c];
        atomicAdd(&st[c], s);
        atomicAdd(&st[HH + c], q);
    }
}

__global__ void k_finalize(float* __restrict__ st, float inv_rows)
{
    int c = threadIdx.x;
    if (c < HH) {
        float mean = st[c] * inv_rows;
        float var  = st[HH + c] * inv_rows - mean * mean;
        st[144 + c] = mean;
        st[216 + c] = rsqrtf(var + EPS_BN);
    }
}

// ---------------- K3: BN+ReLU -> GEMM2+ReLU -> sigmoid gate -> m (in place);
//                  phi_x gate -> trans -> atomics (agg, cnt, magg)
__global__ __launch_bounds__(256) void k_edge_main(
    const float* __restrict__ x,
    const int* __restrict__ ei, const int* __restrict__ ej,
    const float* __restrict__ st1, const float* __restrict__ g1, const float* __restrict__ b1,
    const float* __restrict__ We2, const float* __restrict__ be2,
    const float* __restrict__ Wm, const float* __restrict__ bm,
    const float* __restrict__ Wx1, const float* __restrict__ bx1,
    const float* __restrict__ Wx2,
    float* __restrict__ m,
    float* __restrict__ agg, float* __restrict__ cnt, float* __restrict__ magg)
{
    int row = blockIdx.x * 256 + threadIdx.x;
    int b = row >> 14;
    int i = ei[row];
    const float* mean = st1 + 144;
    const float* inv  = st1 + 216;

    float4* m4 = (float4*)(m + (size_t)row * HH);

    // t = relu( BN(z1) @ We2 + be2 )   (re-reads z1 chunk per k-block; L1-hot)
    float t[HH];
    #pragma unroll
    for (int c = 0; c < HH; c++) t[c] = be2[c];
    for (int kk = 0; kk < 18; kk++) {
        float4 v = ((const float4*)m4)[kk];
        int k = kk * 4;
        float z0 = fmaxf((v.x - mean[k  ]) * inv[k  ] * g1[k  ] + b1[k  ], 0.f);
        float z1v= fmaxf((v.y - mean[k+1]) * inv[k+1] * g1[k+1] + b1[k+1], 0.f);
        float z2v= fmaxf((v.z - mean[k+2]) * inv[k+2] * g1[k+2] + b1[k+2], 0.f);
        float z3v= fmaxf((v.w - mean[k+3]) * inv[k+3] * g1[k+3] + b1[k+3], 0.f);
        const float* w = We2 + k * HH;
        #pragma unroll
        for (int c = 0; c < HH; c++)
            t[c] += z0*w[c] + z1v*w[HH+c] + z2v*w[2*HH+c] + z3v*w[3*HH+c];
    }
    float s = bm[0];
    #pragma unroll
    for (int c = 0; c < HH; c++) { t[c] = fmaxf(t[c], 0.f); s += t[c] * Wm[c]; }
    float sg = 1.f / (1.f + expf(-s));
    #pragma unroll
    for (int c = 0; c < HH; c++) t[c] *= sg;

    // store m (overwrites z1 in place)
    #pragma unroll
    for (int kk = 0; kk < 18; kk++)
        m4[kk] = make_float4(t[4*kk], t[4*kk+1], t[4*kk+2], t[4*kk+3]);

    // u = m @ Wx1 + bx1 ; g2 = relu(u) @ Wx2   (re-read m per chunk)
    float u[HH];
    #pragma unroll
    for (int c = 0; c < HH; c++) u[c] = bx1[c];
    for (int kk = 0; kk < 18; kk++) {
        float4 v = ((const float4*)m4)[kk];
        const float* w = Wx1 + kk * 4 * HH;
        #pragma unroll
        for (int c = 0; c < HH; c++)
            u[c] += v.x*w[c] + v.y*w[HH+c] + v.z*w[2*HH+c] + v.w*w[3*HH+c];
    }
    float g2 = 0.f;
    #pragma unroll
    for (int c = 0; c < HH; c++) g2 += fmaxf(u[c], 0.f) * Wx2[c];

    // trans = clip(x_diff * g2, +-100); scatter
    int j = ej[row];
    float4 xi = *(const float4*)(x + ((size_t)b * NN + i) * 4);
    float4 xj = *(const float4*)(x + ((size_t)b * NN + j) * 4);
    float tr0 = fminf(fmaxf((xi.x - xj.x) * g2, -100.f), 100.f);
    float tr1 = fminf(fmaxf((xi.y - xj.y) * g2, -100.f), 100.f);
    float tr2 = fminf(fmaxf((xi.z - xj.z) * g2, -100.f), 100.f);
    float tr3 = fminf(fmaxf((xi.w - xj.w) * g2, -100.f), 100.f);
    size_t node = (size_t)b * NN + i;
    float* ap = agg + node * 4;
    atomicAdd(ap + 0, tr0);
    atomicAdd(ap + 1, tr1);
    atomicAdd(ap + 2, tr2);
    atomicAdd(ap + 3, tr3);
    atomicAdd(cnt + node, 1.f);
    float* mg = magg + node * HH;
    for (int kk = 0; kk < 18; kk++) {
        float4 v = ((const float4*)m4)[kk];
        atomicAdd(mg + 4*kk + 0, v.x);
        atomicAdd(mg + 4*kk + 1, v.y);
        atomicAdd(mg + 4*kk + 2, v.z);
        atomicAdd(mg + 4*kk + 3, v.w);
    }
}

// ---------------- node MLP first GEMM: z2 = [h, magg, node_attr] @ Wh1 + bh1
__global__ __launch_bounds__(256) void k_node_gemm1(
    const float* __restrict__ h, const float* __restrict__ node_attr,
    const float* __restrict__ magg,
    const float* __restrict__ Wh1, const float* __restrict__ bh1,
    float* __restrict__ z2)
{
    int idx = blockIdx.x * 256 + threadIdx.x;  // < ROWS_N
    float acc[HH];
    #pragma unroll
    for (int c = 0; c < HH; c++) acc[c] = bh1[c];

    const float4* h4 = (const float4*)(h + (size_t)idx * DD);
    for (int kk = 0; kk < 18; kk++) {
        float4 a = h4[kk];
        const float* w = Wh1 + kk * 4 * HH;
        #pragma unroll
        for (int c = 0; c < HH; c++)
            acc[c] += a.x*w[c] + a.y*w[HH+c] + a.z*w[2*HH+c] + a.w*w[3*HH+c];
    }
    const float4* mg4 = (const float4*)(magg + (size_t)idx * HH);
    for (int kk = 0; kk < 18; kk++) {
        float4 a = mg4[kk];
        const float* w = Wh1 + (DD + kk * 4) * HH;
        #pragma unroll
        for (int c = 0; c < HH; c++)
            acc[c] += a.x*w[c] + a.y*w[HH+c] + a.z*w[2*HH+c] + a.w*w[3*HH+c];
    }
    {
        float4 a = *(const float4*)(node_attr + (size_t)idx * 4);
        const float* w = Wh1 + (DD + HH) * HH;
        #pragma unroll
        for (int c = 0; c < HH; c++)
            acc[c] += a.x*w[c] + a.y*w[HH+c] + a.z*w[2*HH+c] + a.w*w[3*HH+c];
    }
    float4* o4 = (float4*)(z2 + (size_t)idx * HH);
    #pragma unroll
    for (int kk = 0; kk < 18; kk++)
        o4[kk] = make_float4(acc[4*kk], acc[4*kk+1], acc[4*kk+2], acc[4*kk+3]);
}

// ---------------- node final: BN2+ReLU -> @Wh2+bh2 -> +h ; x_out = x + agg/max(cnt,1)
__global__ __launch_bounds__(256) void k_node_final(
    const float* __restrict__ h, const float* __restrict__ x,
    const float* __restrict__ z2, const float* __restrict__ st2,
    const float* __restrict__ gh, const float* __restrict__ bh,
    const float* __restrict__ Wh2, const float* __restrict__ bh2,
    const float* __restrict__ agg, const float* __restrict__ cnt,
    float* __restrict__ hout, float* __restrict__ xout)
{
    int idx = blockIdx.x * 256 + threadIdx.x;  // < ROWS_N
    const float* mean = st2 + 144;
    const float* inv  = st2 + 216;

    float t[HH];
    #pragma unroll
    for (int c = 0; c < HH; c++) t[c] = bh2[c];
    const float4* z4 = (const float4*)(z2 + (size_t)idx * HH);
    for (int kk = 0; kk < 18; kk++) {
        float4 v = z4[kk];
        int k = kk * 4;
        float a0 = fmaxf((v.x - mean[k  ]) * inv[k  ] * gh[k  ] + bh[k  ], 0.f);
        float a1 = fmaxf((v.y - mean[k+1]) * inv[k+1] * gh[k+1] + bh[k+1], 0.f);
        float a2 = fmaxf((v.z - mean[k+2]) * inv[k+2] * gh[k+2] + bh[k+2], 0.f);
        float a3 = fmaxf((v.w - mean[k+3]) * inv[k+3] * gh[k+3] + bh[k+3], 0.f);
        const float* w = Wh2 + k * HH;
        #pragma unroll
        for (int c = 0; c < HH; c++)
            t[c] += a0*w[c] + a1*w[HH+c] + a2*w[2*HH+c] + a3*w[3*HH+c];
    }
    const float4* h4 = (const float4*)(h + (size_t)idx * DD);
    float4* ho4 = (float4*)(hout + (size_t)idx * DD);
    #pragma unroll
    for (int kk = 0; kk < 18; kk++) {
        float4 hv = h4[kk];
        ho4[kk] = make_float4(hv.x + t[4*kk], hv.y + t[4*kk+1],
                              hv.z + t[4*kk+2], hv.w + t[4*kk+3]);
    }
    float cn = fmaxf(cnt[idx], 1.f);
    float4 ag = *(const float4*)(agg + (size_t)idx * 4);
    float4 xv = *(const float4*)(x + (size_t)idx * 4);
    ((float4*)xout)[idx] = make_float4(xv.x + ag.x / cn, xv.y + ag.y / cn,
                                       xv.z + ag.z / cn, xv.w + ag.w / cn);
}

extern "C" void kernel_launch(void* const* d_in, const int* in_sizes, int n_in,
                              void* d_out, int out_size, void* d_ws, size_t ws_size,
                              hipStream_t stream)
{
    const float* h   = (const float*)d_in[0];
    const float* x   = (const float*)d_in[1];
    const int*   ei  = (const int*)d_in[2];
    const int*   ej  = (const int*)d_in[3];
    const float* na  = (const float*)d_in[4];
    const float* We1 = (const float*)d_in[5];
    const float* g1  = (const float*)d_in[6];
    const float* b1  = (const float*)d_in[7];
    const float* We2 = (const float*)d_in[8];
    const float* be2 = (const float*)d_in[9];
    const float* Wm  = (const float*)d_in[10];
    const float* bm  = (const float*)d_in[11];
    const float* Wx1 = (const float*)d_in[12];
    const float* bx1 = (const float*)d_in[13];
    const float* Wx2 = (const float*)d_in[14];
    const float* Wh1 = (const float*)d_in[15];
    const float* bh1 = (const float*)d_in[16];
    const float* gh  = (const float*)d_in[17];
    const float* bhp = (const float*)d_in[18];
    const float* Wh2 = (const float*)d_in[19];
    const float* bh2 = (const float*)d_in[20];

    float* out  = (float*)d_out;
    float* hout = out + HOUT_OFF;
    float* xout = out + XOUT_OFF;
    float* m    = out + M_OFF;          // doubles as z1 scratch, then holds m
    float* ws   = (float*)d_ws;
    float* st1  = ws + ST1_OFF;
    float* st2  = ws + ST2_OFF;
    float* agg  = ws + AGG_OFF;
    float* cnt  = ws + CNT_OFF;
    float* magg = ws + MAGG_OFF;
    float* z2   = ws + Z2_OFF;

    hipMemsetAsync(d_ws, 0, (size_t)ZERO_FLOATS * sizeof(float), stream);

    k_edge_gemm1<<<ROWS_E/256, 256, 0, stream>>>(h, x, ei, ej, We1, m);
    k_stats<<<dim3(256), dim3(72, 4), 0, stream>>>(m, ROWS_E, st1);
    k_finalize<<<1, 128, 0, stream>>>(st1, 1.0f / (float)ROWS_E);
    k_edge_main<<<ROWS_E/256, 256, 0, stream>>>(x, ei, ej, st1, g1, b1, We2, be2,
                                                Wm, bm, Wx1, bx1, Wx2,
                                                m, agg, cnt, magg);
    k_node_gemm1<<<ROWS_N/256, 256, 0, stream>>>(h, na, magg, Wh1, bh1, z2);
    k_stats<<<dim3(16), dim3(72, 4), 0, stream>>>(z2, ROWS_N, st2);
    k_finalize<<<1, 128, 0, stream>>>(st2, 1.0f / (float)ROWS_N);
    k_node_final<<<ROWS_N/256, 256, 0, stream>>>(h, x, z2, st2, gh, bhp, Wh2, bh2,
                                                 agg, cnt, hout, xout);
}

// Round 3
// 783.026 us; speedup vs baseline: 4.2079x; 4.2079x over previous
//
#include <hip/hip_runtime.h>

#define BB 32
#define NN 128
#define EE 16384
#define ROWS_E (BB*EE)     // 524288
#define ROWS_N (BB*NN)     // 4096
#define EPS_BN 1e-5f

// d_out layout (floats): h_out, x_out, m
#define XOUT_OFF (ROWS_N*72)
#define M_OFF    (XOUT_OFF + ROWS_N*4)

// ws layout (floats)
#define ST1_OFF 0
#define ST2_OFF 512
#define AGG_OFF 1024
#define CNT_OFF (AGG_OFF + ROWS_N*4)
#define MAGG_OFF (CNT_OFF + ROWS_N)
#define Z2_OFF (MAGG_OFF + ROWS_N*72)     // 316416
#define ZERO_FLOATS Z2_OFF
#define WB_OFF (Z2_OFF + ROWS_N*72)       // 611328 floats; ushort region after

// transposed bf16 weight buffer (ushort offsets)
#define WE1T_OFF 0          // [80][168]
#define WE2T_OFF 13440      // [80][104]
#define WX1T_OFF 21760      // [80][104]
#define WH1T_OFF 30080      // [80][168]
#define WH2T_OFF 43520      // [80][104]
#define WB_TOTAL 51840

typedef __attribute__((ext_vector_type(8))) short short8;
typedef __attribute__((ext_vector_type(4))) float f32x4;

__device__ __forceinline__ float psi_f(float p) {
    return copysignf(log1pf(fabsf(p)), p);
}
__device__ __forceinline__ unsigned short f2bf(float f) {
    union { float f; unsigned u; } v; v.f = f;
    unsigned r = v.u + 0x7fffu + ((v.u >> 16) & 1u);
    return (unsigned short)(r >> 16);
}
__device__ __forceinline__ unsigned pk(float a, float b) {
    return (unsigned)f2bf(a) | ((unsigned)f2bf(b) << 16);
}

// ---------- weight prep: transpose + bf16, pad n->80, k->168/104 with zeros
__global__ void k_prep(const float* __restrict__ We1, const float* __restrict__ We2,
                       const float* __restrict__ Wx1, const float* __restrict__ Wh1,
                       const float* __restrict__ Wh2, unsigned short* __restrict__ wb)
{
    int idx = blockIdx.x * 256 + threadIdx.x;
    if (idx >= WB_TOTAL) return;
    const float* src; int off, n, k, K;
    if (idx < WE2T_OFF)      { off = idx;            n = off/168; k = off%168; src = We1; K = 146; }
    else if (idx < WH1T_OFF && idx >= WX1T_OFF) { off = idx - WX1T_OFF; n = off/104; k = off%104; src = Wx1; K = 72; }
    else if (idx < WX1T_OFF) { off = idx - WE2T_OFF; n = off/104; k = off%104; src = We2; K = 72; }
    else if (idx < WH2T_OFF) { off = idx - WH1T_OFF; n = off/168; k = off%168; src = Wh1; K = 148; }
    else                     { off = idx - WH2T_OFF; n = off/104; k = off%104; src = Wh2; K = 72; }
    float v = (n < 72 && k < K) ? src[k * 72 + n] : 0.f;
    wb[idx] = f2bf(v);
}

// ---------- GEMM1: z1[524288,72] = feat[.,146] @ We1 ; feat gathered + psi feats
__global__ __launch_bounds__(256) void k_edge_gemm1(
    const float* __restrict__ h, const float* __restrict__ x,
    const int* __restrict__ ei, const int* __restrict__ ej,
    const unsigned short* __restrict__ We1t, float* __restrict__ z1)
{
    __shared__ unsigned short At[128 * 168];
    __shared__ unsigned short Wt[80 * 168];
    int tid = threadIdx.x;
    {   // stage weights: 13440 shorts = 1680 uint4 (uint4 = 8 shorts)
        const uint4* s = (const uint4*)We1t; uint4* d = (uint4*)Wt;
        for (int q = tid; q < 1680; q += 256) d[q] = s[q];
    }
    int rl = tid >> 1, half = tid & 1;
    int row = blockIdx.x * 128 + rl;
    int b = row >> 14;
    int i = ei[row], j = ej[row];
    int node = half ? j : i;
    const float4* hp = (const float4*)(h + (size_t)(b * 128 + node) * 72);
    uint2* arow = (uint2*)(&At[rl * 168 + half * 72]);
    #pragma unroll
    for (int q = 0; q < 18; q++) {
        float4 v = hp[q];
        arow[q] = make_uint2(pk(v.x, v.y), pk(v.z, v.w));
    }
    unsigned* tailp = (unsigned*)(&At[rl * 168 + 146]);
    if (half == 0) {
        float4 xi = *(const float4*)(x + (size_t)(b * 128 + i) * 4);
        float4 xj = *(const float4*)(x + (size_t)(b * 128 + j) * 4);
        float d0 = xi.x - xj.x, d1 = xi.y - xj.y, d2 = xi.z - xj.z, d3 = xi.w - xj.w;
        float nrm = d0*d0 - d1*d1 - d2*d2 - d3*d3;
        float dot = xi.x*xj.x - xi.y*xj.y - xi.z*xj.z - xi.w*xj.w;
        *(unsigned*)(&At[rl * 168 + 144]) = pk(psi_f(nrm), psi_f(dot));
        #pragma unroll
        for (int q = 0; q < 6; q++) tailp[q] = 0u;
    } else {
        #pragma unroll
        for (int q = 6; q < 11; q++) tailp[q] = 0u;
    }
    __syncthreads();

    int wv = tid >> 6, lane = tid & 63, c = lane & 15, quad = lane >> 4;
    f32x4 acc[2][5] = {};
    for (int kc = 0; kc < 5; kc++) {
        int k0 = kc * 32 + quad * 8;
        short8 a0 = *(const short8*)(&At[(wv * 32 + c) * 168 + k0]);
        short8 a1 = *(const short8*)(&At[(wv * 32 + 16 + c) * 168 + k0]);
        #pragma unroll
        for (int ct = 0; ct < 5; ct++) {
            short8 bf = *(const short8*)(&Wt[(ct * 16 + c) * 168 + k0]);
            acc[0][ct] = __builtin_amdgcn_mfma_f32_16x16x32_bf16(a0, bf, acc[0][ct], 0, 0, 0);
            acc[1][ct] = __builtin_amdgcn_mfma_f32_16x16x32_bf16(a1, bf, acc[1][ct], 0, 0, 0);
        }
    }
    size_t rbase = (size_t)blockIdx.x * 128 + wv * 32 + quad * 4;
    #pragma unroll
    for (int rt = 0; rt < 2; rt++)
        #pragma unroll
        for (int ct = 0; ct < 5; ct++) {
            int col = ct * 16 + c;
            if (col < 72) {
                float* op = z1 + (rbase + rt * 16) * 72 + col;
                #pragma unroll
                for (int r = 0; r < 4; r++) op[(size_t)r * 72] = acc[rt][ct][r];
            }
        }
}

// ---------- per-channel sum/sumsq (BatchNorm stats)
__global__ void k_stats(const float* __restrict__ z, int rows, float* __restrict__ st)
{
    __shared__ float ssum[4][72];
    __shared__ float ssq[4][72];
    int c = threadIdx.x, ty = threadIdx.y;
    float s = 0.f, q = 0.f;
    for (int r = blockIdx.x * 4 + ty; r < rows; r += gridDim.x * 4) {
        float v = z[(size_t)r * 72 + c];
        s += v; q += v * v;
    }
    ssum[ty][c] = s; ssq[ty][c] = q;
    __syncthreads();
    if (ty == 0) {
        s = ssum[0][c] + ssum[1][c] + ssum[2][c] + ssum[3][c];
        q = ssq[0][c] + ssq[1][c] + ssq[2][c] + ssq[3][c];
        atomicAdd(&st[c], s);
        atomicAdd(&st[72 + c], q);
    }
}

__global__ void k_finalize(float* __restrict__ st, float inv_rows)
{
    int c = threadIdx.x;
    if (c < 72) {
        float mean = st[c] * inv_rows;
        float var  = st[72 + c] * inv_rows - mean * mean;
        st[144 + c] = mean;
        st[216 + c] = rsqrtf(var + EPS_BN);
    }
}

// ---------- edge main: BN+ReLU -> MFMA GEMM2 -> gate -> m ; MFMA GEMM3 -> g2 -> agg/cnt
__global__ __launch_bounds__(256) void k_edge_main(
    const float* __restrict__ x, const int* __restrict__ ei, const int* __restrict__ ej,
    const float* __restrict__ st1, const float* __restrict__ g1, const float* __restrict__ b1,
    const float* __restrict__ be2, const float* __restrict__ Wm, const float* __restrict__ bm,
    const float* __restrict__ bx1, const float* __restrict__ Wx2,
    const unsigned short* __restrict__ We2t, const unsigned short* __restrict__ Wx1t,
    float* __restrict__ m, float* __restrict__ agg, float* __restrict__ cnt)
{
    __shared__ unsigned short Zt[128 * 104];
    __shared__ unsigned short W2[80 * 104];
    __shared__ unsigned short W3[80 * 104];
    __shared__ float g2buf[128];
    int tid = threadIdx.x;
    {   // 8320 shorts = 1040 uint4 each
        const uint4* s2 = (const uint4*)We2t; uint4* d2 = (uint4*)W2;
        const uint4* s3 = (const uint4*)Wx1t; uint4* d3 = (uint4*)W3;
        for (int q = tid; q < 1040; q += 256) { d2[q] = s2[q]; d3[q] = s3[q]; }
    }
    int rl = tid >> 1, half = tid & 1;
    size_t row = (size_t)blockIdx.x * 128 + rl;
    const float* mean = st1 + 144;
    const float* inv  = st1 + 216;
    const float4* zp = (const float4*)(m + row * 72) + half * 9;
    uint2* arow = (uint2*)(&Zt[rl * 104 + half * 36]);
    #pragma unroll
    for (int q = 0; q < 9; q++) {
        int k = half * 36 + q * 4;
        float4 v = zp[q];
        float a0 = fmaxf((v.x - mean[k  ]) * inv[k  ] * g1[k  ] + b1[k  ], 0.f);
        float a1 = fmaxf((v.y - mean[k+1]) * inv[k+1] * g1[k+1] + b1[k+1], 0.f);
        float a2 = fmaxf((v.z - mean[k+2]) * inv[k+2] * g1[k+2] + b1[k+2], 0.f);
        float a3 = fmaxf((v.w - mean[k+3]) * inv[k+3] * g1[k+3] + b1[k+3], 0.f);
        arow[q] = make_uint2(pk(a0, a1), pk(a2, a3));
    }
    uint2* prow = (uint2*)(&Zt[rl * 104]);
    #pragma unroll
    for (int q = 0; q < 4; q++) prow[18 + half * 4 + q] = make_uint2(0u, 0u);
    __syncthreads();

    int wv = tid >> 6, lane = tid & 63, c = lane & 15, quad = lane >> 4;
    // GEMM2
    f32x4 acc2[2][5] = {};
    for (int kc = 0; kc < 3; kc++) {
        int k0 = kc * 32 + quad * 8;
        short8 a0 = *(const short8*)(&Zt[(wv * 32 + c) * 104 + k0]);
        short8 a1 = *(const short8*)(&Zt[(wv * 32 + 16 + c) * 104 + k0]);
        #pragma unroll
        for (int ct = 0; ct < 5; ct++) {
            short8 bf = *(const short8*)(&W2[(ct * 16 + c) * 104 + k0]);
            acc2[0][ct] = __builtin_amdgcn_mfma_f32_16x16x32_bf16(a0, bf, acc2[0][ct], 0, 0, 0);
            acc2[1][ct] = __builtin_amdgcn_mfma_f32_16x16x32_bf16(a1, bf, acc2[1][ct], 0, 0, 0);
        }
    }
    // epilogue: t = relu(acc+be2); gate s = sum t*Wm
    float part[2][4] = {};
    float bm0 = bm[0];
    #pragma unroll
    for (int ct = 0; ct < 5; ct++) {
        int col = ct * 16 + c;
        float bias = (col < 72) ? be2[col] : 0.f;
        float wm   = (col < 72) ? Wm[col]  : 0.f;
        #pragma unroll
        for (int rt = 0; rt < 2; rt++)
            #pragma unroll
            for (int r = 0; r < 4; r++) {
                float t = fmaxf(acc2[rt][ct][r] + bias, 0.f);
                acc2[rt][ct][r] = t;
                part[rt][r] += t * wm;
            }
    }
    float sg[2][4];
    #pragma unroll
    for (int rt = 0; rt < 2; rt++)
        #pragma unroll
        for (int r = 0; r < 4; r++) {
            float s = part[rt][r];
            s += __shfl_xor(s, 1); s += __shfl_xor(s, 2);
            s += __shfl_xor(s, 4); s += __shfl_xor(s, 8);
            sg[rt][r] = 1.f / (1.f + expf(-(s + bm0)));
        }
    // m = t * gate: write global fp32 + LDS bf16 (overwrite own wave's rows)
    size_t rbase = (size_t)blockIdx.x * 128 + wv * 32 + quad * 4;
    #pragma unroll
    for (int rt = 0; rt < 2; rt++)
        #pragma unroll
        for (int ct = 0; ct < 5; ct++) {
            int col = ct * 16 + c;
            #pragma unroll
            for (int r = 0; r < 4; r++) {
                float mv = acc2[rt][ct][r] * sg[rt][r];
                int lrow = wv * 32 + rt * 16 + quad * 4 + r;
                Zt[lrow * 104 + col] = f2bf(mv);
                if (col < 72) m[(rbase + rt * 16 + r) * 72 + col] = mv;
            }
        }
    // GEMM3: u = m @ Wx1  (same wave's rows, no barrier needed)
    f32x4 acc3[2][5] = {};
    for (int kc = 0; kc < 3; kc++) {
        int k0 = kc * 32 + quad * 8;
        short8 a0 = *(const short8*)(&Zt[(wv * 32 + c) * 104 + k0]);
        short8 a1 = *(const short8*)(&Zt[(wv * 32 + 16 + c) * 104 + k0]);
        #pragma unroll
        for (int ct = 0; ct < 5; ct++) {
            short8 bf = *(const short8*)(&W3[(ct * 16 + c) * 104 + k0]);
            acc3[0][ct] = __builtin_amdgcn_mfma_f32_16x16x32_bf16(a0, bf, acc3[0][ct], 0, 0, 0);
            acc3[1][ct] = __builtin_amdgcn_mfma_f32_16x16x32_bf16(a1, bf, acc3[1][ct], 0, 0, 0);
        }
    }
    float part3[2][4] = {};
    #pragma unroll
    for (int ct = 0; ct < 5; ct++) {
        int col = ct * 16 + c;
        float bias = (col < 72) ? bx1[col] : 0.f;
        float wx   = (col < 72) ? Wx2[col] : 0.f;
        #pragma unroll
        for (int rt = 0; rt < 2; rt++)
            #pragma unroll
            for (int r = 0; r < 4; r++)
                part3[rt][r] += fmaxf(acc3[rt][ct][r] + bias, 0.f) * wx;
    }
    #pragma unroll
    for (int rt = 0; rt < 2; rt++)
        #pragma unroll
        for (int r = 0; r < 4; r++) {
            float s = part3[rt][r];
            s += __shfl_xor(s, 1); s += __shfl_xor(s, 2);
            s += __shfl_xor(s, 4); s += __shfl_xor(s, 8);
            if (c == 0) g2buf[wv * 32 + rt * 16 + quad * 4 + r] = s;
        }
    __syncthreads();
    // scatter agg/cnt
    if (tid < 128) {
        size_t erow = (size_t)blockIdx.x * 128 + tid;
        int b = (int)(erow >> 14);
        int i2 = ei[erow], j2 = ej[erow];
        float g2 = g2buf[tid];
        float4 xi = *(const float4*)(x + (size_t)(b * 128 + i2) * 4);
        float4 xj = *(const float4*)(x + (size_t)(b * 128 + j2) * 4);
        float t0 = fminf(fmaxf((xi.x - xj.x) * g2, -100.f), 100.f);
        float t1 = fminf(fmaxf((xi.y - xj.y) * g2, -100.f), 100.f);
        float t2 = fminf(fmaxf((xi.z - xj.z) * g2, -100.f), 100.f);
        float t3 = fminf(fmaxf((xi.w - xj.w) * g2, -100.f), 100.f);
        float* ap = agg + (size_t)(b * 128 + i2) * 4;
        atomicAdd(ap + 0, t0); atomicAdd(ap + 1, t1);
        atomicAdd(ap + 2, t2); atomicAdd(ap + 3, t3);
        atomicAdd(cnt + (size_t)(b * 128 + i2), 1.f);
    }
}

// ---------- magg: segment-sum of m over edges, LDS-staged
__global__ __launch_bounds__(256) void k_magg(
    const float* __restrict__ m, const int* __restrict__ ei, float* __restrict__ magg)
{
    __shared__ float accum[128 * 72];
    int tid = threadIdx.x;
    for (int q = tid; q < 9216; q += 256) accum[q] = 0.f;
    __syncthreads();
    int b = blockIdx.x >> 3, chunk = blockIdx.x & 7;
    int wv = tid >> 6, lane = tid & 63;
    int ebase = b * 16384 + chunk * 2048;
    for (int e = wv; e < 2048; e += 4) {
        int erow = ebase + e;
        int node = ei[erow];
        const float* mr = m + (size_t)erow * 72;
        atomicAdd(&accum[node * 72 + lane], mr[lane]);
        if (lane < 8) atomicAdd(&accum[node * 72 + 64 + lane], mr[64 + lane]);
    }
    __syncthreads();
    float* mg = magg + (size_t)b * 9216;
    for (int q = tid; q < 9216; q += 256) atomicAdd(&mg[q], accum[q]);
}

// ---------- node GEMM1: z2 = [h, magg, node_attr] @ Wh1 + bh1
__global__ __launch_bounds__(256) void k_node_gemm1(
    const float* __restrict__ h, const float* __restrict__ node_attr,
    const float* __restrict__ magg, const unsigned short* __restrict__ Wh1t,
    const float* __restrict__ bh1, float* __restrict__ z2)
{
    __shared__ unsigned short At[128 * 168];
    __shared__ unsigned short Wt[80 * 168];
    int tid = threadIdx.x;
    {
        const uint4* s = (const uint4*)Wh1t; uint4* d = (uint4*)Wt;
        for (int q = tid; q < 1680; q += 256) d[q] = s[q];
    }
    int rl = tid >> 1, half = tid & 1;
    size_t row = (size_t)blockIdx.x * 128 + rl;
    const float4* sp = (const float4*)((half ? magg : h) + row * 72);
    uint2* arow = (uint2*)(&At[rl * 168 + half * 72]);
    #pragma unroll
    for (int q = 0; q < 18; q++) {
        float4 v = sp[q];
        arow[q] = make_uint2(pk(v.x, v.y), pk(v.z, v.w));
    }
    if (half) {
        float4 na = *(const float4*)(node_attr + row * 4);
        *(unsigned*)(&At[rl * 168 + 144]) = pk(na.x, na.y);
        *(unsigned*)(&At[rl * 168 + 146]) = pk(na.z, na.w);
        unsigned* tailp = (unsigned*)(&At[rl * 168 + 148]);
        #pragma unroll
        for (int q = 0; q < 10; q++) tailp[q] = 0u;
    }
    __syncthreads();

    int wv = tid >> 6, lane = tid & 63, c = lane & 15, quad = lane >> 4;
    f32x4 acc[2][5] = {};
    for (int kc = 0; kc < 5; kc++) {
        int k0 = kc * 32 + quad * 8;
        short8 a0 = *(const short8*)(&At[(wv * 32 + c) * 168 + k0]);
        short8 a1 = *(const short8*)(&At[(wv * 32 + 16 + c) * 168 + k0]);
        #pragma unroll
        for (int ct = 0; ct < 5; ct++) {
            short8 bf = *(const short8*)(&Wt[(ct * 16 + c) * 168 + k0]);
            acc[0][ct] = __builtin_amdgcn_mfma_f32_16x16x32_bf16(a0, bf, acc[0][ct], 0, 0, 0);
            acc[1][ct] = __builtin_amdgcn_mfma_f32_16x16x32_bf16(a1, bf, acc[1][ct], 0, 0, 0);
        }
    }
    size_t rbase = (size_t)blockIdx.x * 128 + wv * 32 + quad * 4;
    #pragma unroll
    for (int rt = 0; rt < 2; rt++)
        #pragma unroll
        for (int ct = 0; ct < 5; ct++) {
            int col = ct * 16 + c;
            if (col < 72) {
                float bias = bh1[col];
                float* op = z2 + (rbase + rt * 16) * 72 + col;
                #pragma unroll
                for (int r = 0; r < 4; r++) op[(size_t)r * 72] = acc[rt][ct][r] + bias;
            }
        }
}

// ---------- node final: BN2+ReLU -> MFMA @Wh2 + bh2 + h ; x_out
__global__ __launch_bounds__(256) void k_node_final(
    const float* __restrict__ h, const float* __restrict__ x,
    const float* __restrict__ z2, const float* __restrict__ st2,
    const float* __restrict__ gh, const float* __restrict__ bh,
    const unsigned short* __restrict__ Wh2t, const float* __restrict__ bh2,
    const float* __restrict__ agg, const float* __restrict__ cnt,
    float* __restrict__ hout, float* __restrict__ xout)
{
    __shared__ unsigned short Zt[128 * 104];
    __shared__ unsigned short Wt[80 * 104];
    int tid = threadIdx.x;
    {
        const uint4* s = (const uint4*)Wh2t; uint4* d = (uint4*)Wt;
        for (int q = tid; q < 1040; q += 256) d[q] = s[q];
    }
    int rl = tid >> 1, half = tid & 1;
    size_t row = (size_t)blockIdx.x * 128 + rl;
    const float* mean = st2 + 144;
    const float* inv  = st2 + 216;
    const float4* zp = (const float4*)(z2 + row * 72) + half * 9;
    uint2* arow = (uint2*)(&Zt[rl * 104 + half * 36]);
    #pragma unroll
    for (int q = 0; q < 9; q++) {
        int k = half * 36 + q * 4;
        float4 v = zp[q];
        float a0 = fmaxf((v.x - mean[k  ]) * inv[k  ] * gh[k  ] + bh[k  ], 0.f);
        float a1 = fmaxf((v.y - mean[k+1]) * inv[k+1] * gh[k+1] + bh[k+1], 0.f);
        float a2 = fmaxf((v.z - mean[k+2]) * inv[k+2] * gh[k+2] + bh[k+2], 0.f);
        float a3 = fmaxf((v.w - mean[k+3]) * inv[k+3] * gh[k+3] + bh[k+3], 0.f);
        arow[q] = make_uint2(pk(a0, a1), pk(a2, a3));
    }
    uint2* prow = (uint2*)(&Zt[rl * 104]);
    #pragma unroll
    for (int q = 0; q < 4; q++) prow[18 + half * 4 + q] = make_uint2(0u, 0u);
    __syncthreads();

    int wv = tid >> 6, lane = tid & 63, c = lane & 15, quad = lane >> 4;
    f32x4 acc[2][5] = {};
    for (int kc = 0; kc < 3; kc++) {
        int k0 = kc * 32 + quad * 8;
        short8 a0 = *(const short8*)(&Zt[(wv * 32 + c) * 104 + k0]);
        short8 a1 = *(const short8*)(&Zt[(wv * 32 + 16 + c) * 104 + k0]);
        #pragma unroll
        for (int ct = 0; ct < 5; ct++) {
            short8 bf = *(const short8*)(&Wt[(ct * 16 + c) * 104 + k0]);
            acc[0][ct] = __builtin_amdgcn_mfma_f32_16x16x32_bf16(a0, bf, acc[0][ct], 0, 0, 0);
            acc[1][ct] = __builtin_amdgcn_mfma_f32_16x16x32_bf16(a1, bf, acc[1][ct], 0, 0, 0);
        }
    }
    size_t rbase = (size_t)blockIdx.x * 128 + wv * 32 + quad * 4;
    #pragma unroll
    for (int rt = 0; rt < 2; rt++)
        #pragma unroll
        for (int ct = 0; ct < 5; ct++) {
            int col = ct * 16 + c;
            if (col < 72) {
                float bias = bh2[col];
                #pragma unroll
                for (int r = 0; r < 4; r++) {
                    size_t gr = (rbase + rt * 16 + r);
                    hout[gr * 72 + col] = h[gr * 72 + col] + acc[rt][ct][r] + bias;
                }
            }
        }
    if (tid < 128) {
        size_t nrow = (size_t)blockIdx.x * 128 + tid;
        float cn = fmaxf(cnt[nrow], 1.f);
        float4 ag = *(const float4*)(agg + nrow * 4);
        float4 xv = *(const float4*)(x + nrow * 4);
        ((float4*)xout)[nrow] = make_float4(xv.x + ag.x / cn, xv.y + ag.y / cn,
                                            xv.z + ag.z / cn, xv.w + ag.w / cn);
    }
}

extern "C" void kernel_launch(void* const* d_in, const int* in_sizes, int n_in,
                              void* d_out, int out_size, void* d_ws, size_t ws_size,
                              hipStream_t stream)
{
    const float* h   = (const float*)d_in[0];
    const float* x   = (const float*)d_in[1];
    const int*   ei  = (const int*)d_in[2];
    const int*   ej  = (const int*)d_in[3];
    const float* na  = (const float*)d_in[4];
    const float* We1 = (const float*)d_in[5];
    const float* g1  = (const float*)d_in[6];
    const float* b1  = (const float*)d_in[7];
    const float* We2 = (const float*)d_in[8];
    const float* be2 = (const float*)d_in[9];
    const float* Wm  = (const float*)d_in[10];
    const float* bm  = (const float*)d_in[11];
    const float* Wx1 = (const float*)d_in[12];
    const float* bx1 = (const float*)d_in[13];
    const float* Wx2 = (const float*)d_in[14];
    const float* Wh1 = (const float*)d_in[15];
    const float* bh1 = (const float*)d_in[16];
    const float* gh  = (const float*)d_in[17];
    const float* bhp = (const float*)d_in[18];
    const float* Wh2 = (const float*)d_in[19];
    const float* bh2 = (const float*)d_in[20];

    float* out  = (float*)d_out;
    float* hout = out;
    float* xout = out + XOUT_OFF;
    float* m    = out + M_OFF;          // z1 scratch, then m
    float* ws   = (float*)d_ws;
    float* st1  = ws + ST1_OFF;
    float* st2  = ws + ST2_OFF;
    float* agg  = ws + AGG_OFF;
    float* cnt  = ws + CNT_OFF;
    float* magg = ws + MAGG_OFF;
    float* z2   = ws + Z2_OFF;
    unsigned short* wb = (unsigned short*)(ws + WB_OFF);

    hipMemsetAsync(d_ws, 0, (size_t)ZERO_FLOATS * sizeof(float), stream);
    k_prep<<<(WB_TOTAL + 255) / 256, 256, 0, stream>>>(We1, We2, Wx1, Wh1, Wh2, wb);
    k_edge_gemm1<<<ROWS_E / 128, 256, 0, stream>>>(h, x, ei, ej, wb + WE1T_OFF, m);
    k_stats<<<dim3(1024), dim3(72, 4), 0, stream>>>(m, ROWS_E, st1);
    k_finalize<<<1, 128, 0, stream>>>(st1, 1.0f / (float)ROWS_E);
    k_edge_main<<<ROWS_E / 128, 256, 0, stream>>>(x, ei, ej, st1, g1, b1, be2, Wm, bm,
                                                  bx1, Wx2, wb + WE2T_OFF, wb + WX1T_OFF,
                                                  m, agg, cnt);
    k_magg<<<256, 256, 0, stream>>>(m, ei, magg);
    k_node_gemm1<<<ROWS_N / 128, 256, 0, stream>>>(h, na, magg, wb + WH1T_OFF, bh1, z2);
    k_stats<<<dim3(16), dim3(72, 4), 0, stream>>>(z2, ROWS_N, st2);
    k_finalize<<<1, 128, 0, stream>>>(st2, 1.0f / (float)ROWS_N);
    k_node_final<<<ROWS_N / 128, 256, 0, stream>>>(h, x, z2, st2, gh, bhp,
                                                   wb + WH2T_OFF, bh2, agg, cnt, hout, xout);
}